// Round 3
// baseline (666.526 us; speedup 1.0000x reference)
//
#include <hip/hip_runtime.h>
#include <hip/hip_bf16.h>
#include <stdint.h>

// GatedScreeningTile: B=2 N=2048 DIM=2048 H=16 DK=64 DV=128 DIM_INNER=3072
// Pipeline: cvt/transpose -> GEMM(qg) GEMM(kv) -> normalize -> fused screened-attention -> GEMM(out)

typedef unsigned short u16;
typedef __bf16 bf16x8 __attribute__((ext_vector_type(8)));
typedef u16 u16x8 __attribute__((ext_vector_type(8)));
typedef float f32x4 __attribute__((ext_vector_type(4)));

#define DEVINL __device__ __forceinline__

DEVINL u16 f2bf(float f) {
  union { float f; uint32_t u; } v; v.f = f;
  uint32_t r = (v.u + 0x7FFFu + ((v.u >> 16) & 1u)) >> 16;
  return (u16)r;
}
DEVINL float bf2f(u16 x) {
  union { uint32_t u; float f; } v; v.u = ((uint32_t)x) << 16;
  return v.f;
}
DEVINL bf16x8 as_bf(u16x8 v) { return __builtin_bit_cast(bf16x8, v); }

typedef const __attribute__((address_space(1))) uint32_t* gptr_t;
typedef __attribute__((address_space(3))) uint32_t* lptr_t;
DEVINL void gload_lds16(const void* g, void* l) {
  __builtin_amdgcn_global_load_lds((gptr_t)g, (lptr_t)l, 16, 0, 0);
}

DEVINL f32x4 mfma16(u16x8 a, u16x8 b, f32x4 c) {
  return __builtin_amdgcn_mfma_f32_16x16x32_bf16(as_bf(a), as_bf(b), c, 0, 0, 0);
}

// ---------------- fp32 -> bf16 convert (same layout) ----------------
__global__ void k_cvt(const float* __restrict__ src, u16* __restrict__ dst, int n) {
  int i = (blockIdx.x * blockDim.x + threadIdx.x) * 4;
  int stride = gridDim.x * blockDim.x * 4;
  for (; i < n; i += stride) {
    float4 f = *(const float4*)(src + i);
    ushort4 o;
    o.x = f2bf(f.x); o.y = f2bf(f.y); o.z = f2bf(f.z); o.w = f2bf(f.w);
    *(ushort4*)(dst + i) = o;
  }
}

// ---------------- fp32 (RxC) -> bf16 transposed (CxR) ----------------
__global__ void k_cvtT(const float* __restrict__ src, u16* __restrict__ dst, int R, int C) {
  __shared__ float tile[32][33];
  int c0 = blockIdx.x * 32, r0 = blockIdx.y * 32;
  int tc = threadIdx.x & 31, tr = threadIdx.x >> 5;  // tr 0..7
#pragma unroll
  for (int i = 0; i < 4; i++) {
    int r = tr + i * 8;
    tile[r][tc] = src[(size_t)(r0 + r) * C + c0 + tc];
  }
  __syncthreads();
#pragma unroll
  for (int i = 0; i < 4; i++) {
    int r = tr + i * 8;  // row in dst tile (= src col)
    dst[(size_t)(c0 + r) * R + r0 + tc] = f2bf(tile[tc][r]);
  }
}

// ---------------- bf16 GEMM: C(MxNt) = A(MxK,row-major) * Bt(NtxK,row-major)^T ----------------
// 128x128 tile, BK=32, 4 waves (2x2), 16x16x32 MFMA, global_load_lds staging.
template <int F32OUT>
__global__ __launch_bounds__(256, 2) void k_gemm(const u16* __restrict__ A,
                                                 const u16* __restrict__ Bt,
                                                 void* __restrict__ Cout,
                                                 int M, int Nt, int K) {
  __shared__ u16 As[128 * 32];
  __shared__ u16 Bs[128 * 32];
  const int tid = threadIdx.x, lane = tid & 63, wid = tid >> 6;
  const int m0 = blockIdx.y * 128, n0 = blockIdx.x * 128;
  const int wm = (wid >> 1) * 64, wn = (wid & 1) * 64;
  const int fr = lane & 15, fc = (lane >> 4) * 8;

  f32x4 acc[4][4] = {};

  // staging: wave wid covers rows [wid*32, wid*32+32), 2 insts of 1KB each
  const u16* gA = A + (size_t)(m0 + wid * 32 + (lane >> 2)) * K + (lane & 3) * 8;
  const u16* gB = Bt + (size_t)(n0 + wid * 32 + (lane >> 2)) * K + (lane & 3) * 8;
  u16* lA = As + wid * 1024;
  u16* lB = Bs + wid * 1024;
  const size_t rowskip = (size_t)16 * K;

  for (int k0 = 0; k0 < K; k0 += 32) {
    gload_lds16(gA + k0, lA);
    gload_lds16(gA + k0 + rowskip, lA + 512);
    gload_lds16(gB + k0, lB);
    gload_lds16(gB + k0 + rowskip, lB + 512);
    __syncthreads();
    u16x8 a[4], b[4];
#pragma unroll
    for (int mi = 0; mi < 4; mi++) a[mi] = *(const u16x8*)(As + (wm + mi * 16 + fr) * 32 + fc);
#pragma unroll
    for (int ni = 0; ni < 4; ni++) b[ni] = *(const u16x8*)(Bs + (wn + ni * 16 + fr) * 32 + fc);
#pragma unroll
    for (int mi = 0; mi < 4; mi++)
#pragma unroll
      for (int ni = 0; ni < 4; ni++)
        acc[mi][ni] = mfma16(a[mi], b[ni], acc[mi][ni]);
    __syncthreads();
  }

  const int frow = (lane >> 4) * 4;
#pragma unroll
  for (int mi = 0; mi < 4; mi++)
#pragma unroll
    for (int ni = 0; ni < 4; ni++)
#pragma unroll
      for (int j = 0; j < 4; j++) {
        const size_t row = m0 + wm + mi * 16 + frow + j;
        const size_t col = n0 + wn + ni * 16 + fr;
        if (F32OUT) ((float*)Cout)[row * Nt + col] = acc[mi][ni][j];
        else ((u16*)Cout)[row * Nt + col] = f2bf(acc[mi][ni][j]);
      }
}

// ---------------- normalize: qg/kv raw -> qn, kn, vnT, gact ----------------
// block = (64-n chunk, hb). 4 waves; each wave handles 16 n values serially.
// vnT transposed through a swizzled LDS tile so global writes are 128B-contiguous.
__global__ __launch_bounds__(256, 4) void k_norm(const u16* __restrict__ qg,
                                                 const u16* __restrict__ kv,
                                                 u16* __restrict__ qn, u16* __restrict__ kn,
                                                 u16* __restrict__ vnT, u16* __restrict__ gact) {
  __shared__ u16 vt[128 * 64];  // [d][nl], col swizzle: c' = nl ^ ((d&15)<<2)
  const int tid = threadIdx.x, lane = tid & 63, wid = tid >> 6;
  const int hb = blockIdx.y;            // b*16 + h
  const int h = hb & 15, b = hb >> 4;
  const int n0 = blockIdx.x * 64;

  for (int s = 0; s < 16; s++) {
    const int nl = wid * 16 + s;        // 0..63
    const int n = n0 + nl;
    const size_t bn = (size_t)b * 2048 + n;
    const size_t base = bn * 3072 + (size_t)h * 192;

    float q = bf2f(qg[base + lane]);
    float g0 = bf2f(qg[base + 64 + lane]);
    float g1 = bf2f(qg[base + 128 + lane]);
    float k = bf2f(kv[base + lane]);
    float v0 = bf2f(kv[base + 64 + lane]);
    float v1 = bf2f(kv[base + 128 + lane]);

    float qs = q * q, ks = k * k, vs = v0 * v0 + v1 * v1;
#pragma unroll
    for (int m = 1; m < 64; m <<= 1) {
      qs += __shfl_xor(qs, m);
      ks += __shfl_xor(ks, m);
      vs += __shfl_xor(vs, m);
    }
    float rq = 1.f / fmaxf(sqrtf(qs), 1e-12f);
    float rk = 1.f / fmaxf(sqrtf(ks), 1e-12f);
    float rv = 1.f / fmaxf(sqrtf(vs), 1e-12f);

    qn[((size_t)hb * 2048 + n) * 64 + lane] = f2bf(q * rq);
    kn[((size_t)hb * 2048 + n) * 64 + lane] = f2bf(k * rk);
    float s0 = g0 / (1.f + __expf(-g0));
    float s1 = g1 / (1.f + __expf(-g1));
    gact[((size_t)hb * 2048 + n) * 128 + lane] = f2bf(tanhf(s0));
    gact[((size_t)hb * 2048 + n) * 128 + 64 + lane] = f2bf(tanhf(s1));

    const int d0 = lane, d1 = 64 + lane;
    vt[d0 * 64 + (nl ^ ((d0 & 15) << 2))] = f2bf(v0 * rv);
    vt[d1 * 64 + (nl ^ ((d1 & 15) << 2))] = f2bf(v1 * rv);
  }
  __syncthreads();

  // write-out: 8 passes, 16 lanes per d-row write 4 n each (128B contiguous)
#pragma unroll
  for (int p = 0; p < 8; p++) {
    const int d = p * 16 + (tid >> 4);
    const int nq = (tid & 15) * 4;
    const int cb = nq ^ ((d & 15) << 2);
    ushort4 o;
    o.x = vt[d * 64 + cb + 0];
    o.y = vt[d * 64 + cb + 1];
    o.z = vt[d * 64 + cb + 2];
    o.w = vt[d * 64 + cb + 3];
    *(ushort4*)(vnT + ((size_t)hb * 128 + d) * 2048 + n0 + nq) = o;
  }
}

// ---------------- fused screened attention ----------------
// grid (N/128, B*H), 256 threads (4 waves). Q in regs; K,VT,P in LDS, all XOR-swizzled.
// KVBLK=64: LDS = 8K(Ks) + 16K(Vs) + 16K(Ps) = 40KB -> 4 blocks/CU (16 waves/CU).
__global__ __launch_bounds__(256, 4) void k_attn(const u16* __restrict__ qn,
                                                 const u16* __restrict__ kn,
                                                 const u16* __restrict__ vnT,
                                                 const u16* __restrict__ gact,
                                                 const float* __restrict__ ls_iaw,
                                                 const float* __restrict__ ls_hws,
                                                 u16* __restrict__ pre_out) {
  extern __shared__ char smem[];
  u16* Ks = (u16*)smem;                  // [64 k][64 dk]   rows 128B, 8 chunks, swizzled
  u16* Vs = (u16*)(smem + 8192);         // [128 d][64 k]   rows 128B, swizzled
  u16* Ps = (u16*)(smem + 24576);        // [128 q][64 k]   rows 128B, swizzled
  float* nbuf = (float*)(smem + 24576);  // reuse after loop: [2][128]

  const int tid = threadIdx.x, lane = tid & 63, wid = tid >> 6;
  const int bh = blockIdx.y, h = bh & 15;
  const int n0 = blockIdx.x * 128;
  const int wq = (wid >> 1) * 64;
  const int wckv = (wid & 1) * 32;   // QK: this wave's kv-half (32 wide)
  const int wcd = (wid & 1) * 64;    // PV: this wave's d-half (64 wide)
  const float r = 1.f / (__expf(ls_iaw[h]) + 1.f);
  const float whs = __expf(ls_hws[h]);
  const int fr = lane & 15, hi = lane >> 4, fc = hi * 8, frow = hi * 4;
  const int rb = fr & 7;

  // Q fragments in registers (reused across all KV tiles)
  const u16* qbase = qn + ((size_t)bh * 2048 + n0) * 64;
  u16x8 qf[4][2];
#pragma unroll
  for (int mi = 0; mi < 4; mi++)
#pragma unroll
    for (int kk = 0; kk < 2; kk++)
      qf[mi][kk] = *(const u16x8*)(qbase + (wq + mi * 16 + fr) * 64 + kk * 32 + fc);

  f32x4 acc[4][4] = {};
  const u16* kbase = kn + (size_t)bh * 2048 * 64;
  const u16* vbase = vnT + (size_t)bh * 128 * 2048;

  // staging per-lane constants (inverse-swizzled global offsets, u16 units)
  int ks_goff[2];   // K: 2 x 1KB insts/wave; row = wid*16 + i*8 + (lane>>3)
#pragma unroll
  for (int i = 0; i < 2; i++) {
    int row = wid * 16 + i * 8 + (lane >> 3);
    ks_goff[i] = row * 64 + (((lane & 7) ^ (row & 7)) << 3);
  }
  int vs_goff[4];   // V: 4 x 1KB insts/wave; row = wid*32 + i*8 + (lane>>3)
#pragma unroll
  for (int i = 0; i < 4; i++) {
    int row = wid * 32 + i * 8 + (lane >> 3);
    vs_goff[i] = row * 2048 + (((lane & 7) ^ (row & 7)) << 3);
  }

  for (int t = 0; t < 32; t++) {
    const int kv0 = t * 64;
#pragma unroll
    for (int i = 0; i < 2; i++)
      gload_lds16(kbase + (size_t)kv0 * 64 + ks_goff[i], Ks + wid * 1024 + i * 512);
#pragma unroll
    for (int i = 0; i < 4; i++)
      gload_lds16(vbase + (size_t)vs_goff[i] + kv0, Vs + wid * 2048 + i * 512);
    __syncthreads();

    // sim = q @ k^T for this wave's (wq, wckv)
    f32x4 s[4][2] = {};
    __builtin_amdgcn_s_setprio(1);
#pragma unroll
    for (int kk = 0; kk < 2; kk++) {
      u16x8 kf[2];
#pragma unroll
      for (int ni = 0; ni < 2; ni++) {
        const int row = wckv + ni * 16 + fr;
        kf[ni] = *(const u16x8*)(Ks + row * 64 + (((kk * 4 + hi) ^ rb) << 3));
      }
#pragma unroll
      for (int mi = 0; mi < 4; mi++)
#pragma unroll
        for (int ni = 0; ni < 2; ni++)
          s[mi][ni] = mfma16(qf[mi][kk], kf[ni], s[mi][ni]);
    }
    __builtin_amdgcn_s_setprio(0);

    // screen + write P to LDS (swizzled)
#pragma unroll
    for (int mi = 0; mi < 4; mi++)
#pragma unroll
      for (int ni = 0; ni < 2; ni++)
#pragma unroll
        for (int j = 0; j < 4; j++) {
          const int row = wq + mi * 16 + frow + j;
          const int col = wckv + ni * 16 + fr;
          float p = fmaxf(0.f, 1.f - r * (1.f - s[mi][ni][j]));
          Ps[row * 64 + (col ^ ((row & 7) << 3))] = f2bf(p * p);
        }
    __syncthreads();

    // PV: acc += P @ V  (wcd = this wave's d-half)
    __builtin_amdgcn_s_setprio(1);
#pragma unroll
    for (int kk = 0; kk < 2; kk++) {
      u16x8 pf[4], vf[4];
#pragma unroll
      for (int mi = 0; mi < 4; mi++) {
        const int row = wq + mi * 16 + fr;
        pf[mi] = *(const u16x8*)(Ps + row * 64 + (((kk * 4 + hi) ^ rb) << 3));
      }
#pragma unroll
      for (int ni = 0; ni < 4; ni++) {
        const int row = wcd + ni * 16 + fr;
        vf[ni] = *(const u16x8*)(Vs + row * 64 + (((kk * 4 + hi) ^ rb) << 3));
      }
#pragma unroll
      for (int mi = 0; mi < 4; mi++)
#pragma unroll
        for (int ni = 0; ni < 4; ni++)
          acc[mi][ni] = mfma16(pf[mi], vf[ni], acc[mi][ni]);
    }
    __builtin_amdgcn_s_setprio(0);
    __syncthreads();
  }

  // epilogue: tanh_norm(aggr) * gact * exp(ls_hws) -> pre_out[(b*N+n)][h*128+d]
#pragma unroll
  for (int mi = 0; mi < 4; mi++)
#pragma unroll
    for (int j = 0; j < 4; j++) {
      float ss = 0.f;
#pragma unroll
      for (int ni = 0; ni < 4; ni++) { float x = acc[mi][ni][j]; ss += x * x; }
#pragma unroll
      for (int m = 1; m < 16; m <<= 1) ss += __shfl_xor(ss, m);
      if (fr == 0) nbuf[(wid & 1) * 128 + wq + mi * 16 + frow + j] = ss;
    }
  __syncthreads();

  const size_t gbase = ((size_t)bh * 2048 + n0) * 128;
  const size_t obase = ((size_t)(bh >> 4) * 2048 + n0);
#pragma unroll
  for (int mi = 0; mi < 4; mi++)
#pragma unroll
    for (int j = 0; j < 4; j++) {
      const int row = wq + mi * 16 + frow + j;
      float nsq = nbuf[row] + nbuf[128 + row];
      float nn = sqrtf(nsq);
      float scale = tanhf(nn) / fmaxf(nn, 1e-12f) * whs;
#pragma unroll
      for (int ni = 0; ni < 4; ni++) {
        const int d = wcd + ni * 16 + fr;
        float gv = bf2f(gact[gbase + (size_t)row * 128 + d]);
        pre_out[(obase + row) * 2048 + h * 128 + d] = f2bf(acc[mi][ni][j] * scale * gv);
      }
    }
}

extern "C" void kernel_launch(void* const* d_in, const int* in_sizes, int n_in,
                              void* d_out, int out_size, void* d_ws, size_t ws_size,
                              hipStream_t stream) {
  (void)in_sizes; (void)n_in; (void)out_size; (void)ws_size;
  const float* tokens = (const float*)d_in[0];
  const float* Wqg = (const float*)d_in[1];
  const float* Wkv = (const float*)d_in[2];
  const float* Wo = (const float*)d_in[3];
  const float* ls_iaw = (const float*)d_in[4];
  const float* ls_hws = (const float*)d_in[5];
  float* out = (float*)d_out;
  char* ws = (char*)d_ws;

  // workspace layout (phased aliasing, total 104 MB):
  u16* WoT = (u16*)(ws + 0);                     // 8,388,608 B
  char* regA = ws + 8388608;                     // 50,331,648 B
  u16* tok_bf = (u16*)(regA);                    // phase A-B
  u16* WqgT = (u16*)(regA + 16777216);
  u16* WkvT = (u16*)(regA + 29360128);
  u16* qn = (u16*)(regA);                        // phase C-D
  u16* kn = (u16*)(regA + 8388608);
  u16* vnT = (u16*)(regA + 16777216);
  u16* gact = (u16*)(regA + 33554432);
  char* regB = ws + 58720256;                    // 50,331,648 B
  u16* qg_raw = (u16*)(regB);                    // phase B-C
  u16* kv_raw = (u16*)(regB + 25165824);
  u16* pre_out = (u16*)(regB);                   // phase D-E

  k_cvt<<<4096, 256, 0, stream>>>(tokens, tok_bf, 8388608);
  k_cvtT<<<dim3(96, 64), 256, 0, stream>>>(Wqg, WqgT, 2048, 3072);
  k_cvtT<<<dim3(96, 64), 256, 0, stream>>>(Wkv, WkvT, 2048, 3072);
  k_cvtT<<<dim3(64, 64), 256, 0, stream>>>(Wo, WoT, 2048, 2048);

  k_gemm<0><<<dim3(24, 32), 256, 0, stream>>>(tok_bf, WqgT, qg_raw, 4096, 3072, 2048);
  k_gemm<0><<<dim3(24, 32), 256, 0, stream>>>(tok_bf, WkvT, kv_raw, 4096, 3072, 2048);

  k_norm<<<dim3(32, 32), 256, 0, stream>>>(qg_raw, kv_raw, qn, kn, vnT, gact);

  k_attn<<<dim3(16, 32), 256, 40960, stream>>>(qn, kn, vnT, gact, ls_iaw, ls_hws, pre_out);

  k_gemm<1><<<dim3(16, 32), 256, 0, stream>>>(pre_out, WoT, out, 4096, 2048, 2048);
}

// Round 5
// 309.619 us; speedup vs baseline: 2.1527x; 2.1527x over previous
//
#include <hip/hip_runtime.h>
#include <hip/hip_bf16.h>
#include <stdint.h>

// GatedScreeningTile: B=2 N=2048 DIM=2048 H=16 DK=64 DV=128 DIM_INNER=3072
// Pipeline: cvt/transpose -> GEMM(qg) GEMM(kv) -> normalize -> fused screened-attention -> GEMM(out)

typedef unsigned short u16;
typedef __bf16 bf16x8 __attribute__((ext_vector_type(8)));
typedef u16 u16x8 __attribute__((ext_vector_type(8)));
typedef float f32x4 __attribute__((ext_vector_type(4)));

#define DEVINL __device__ __forceinline__

DEVINL u16 f2bf(float f) {
  union { float f; uint32_t u; } v; v.f = f;
  uint32_t r = (v.u + 0x7FFFu + ((v.u >> 16) & 1u)) >> 16;
  return (u16)r;
}
DEVINL float bf2f(u16 x) {
  union { uint32_t u; float f; } v; v.u = ((uint32_t)x) << 16;
  return v.f;
}
DEVINL bf16x8 as_bf(u16x8 v) { return __builtin_bit_cast(bf16x8, v); }

typedef const __attribute__((address_space(1))) uint32_t* gptr_t;
typedef __attribute__((address_space(3))) uint32_t* lptr_t;
DEVINL void gload_lds16(const void* g, void* l) {
  __builtin_amdgcn_global_load_lds((gptr_t)g, (lptr_t)l, 16, 0, 0);
}

DEVINL f32x4 mfma16(u16x8 a, u16x8 b, f32x4 c) {
  return __builtin_amdgcn_mfma_f32_16x16x32_bf16(as_bf(a), as_bf(b), c, 0, 0, 0);
}

// ---------------- fp32 -> bf16 convert (same layout) ----------------
__global__ void k_cvt(const float* __restrict__ src, u16* __restrict__ dst, int n) {
  int i = (blockIdx.x * blockDim.x + threadIdx.x) * 4;
  int stride = gridDim.x * blockDim.x * 4;
  for (; i < n; i += stride) {
    float4 f = *(const float4*)(src + i);
    ushort4 o;
    o.x = f2bf(f.x); o.y = f2bf(f.y); o.z = f2bf(f.z); o.w = f2bf(f.w);
    *(ushort4*)(dst + i) = o;
  }
}

// ---------------- fp32 (RxC) -> bf16 transposed (CxR) ----------------
__global__ void k_cvtT(const float* __restrict__ src, u16* __restrict__ dst, int R, int C) {
  __shared__ float tile[32][33];
  int c0 = blockIdx.x * 32, r0 = blockIdx.y * 32;
  int tc = threadIdx.x & 31, tr = threadIdx.x >> 5;  // tr 0..7
#pragma unroll
  for (int i = 0; i < 4; i++) {
    int r = tr + i * 8;
    tile[r][tc] = src[(size_t)(r0 + r) * C + c0 + tc];
  }
  __syncthreads();
#pragma unroll
  for (int i = 0; i < 4; i++) {
    int r = tr + i * 8;  // row in dst tile (= src col)
    dst[(size_t)(c0 + r) * R + r0 + tc] = f2bf(tile[tc][r]);
  }
}

// ---------------- bf16 GEMM: C(MxNt) = A(MxK,row-major) * Bt(NtxK,row-major)^T ----------------
// 128x128 tile, BK=32, 4 waves (2x2), 16x16x32 MFMA, global_load_lds staging.
template <int F32OUT>
__global__ __launch_bounds__(256, 2) void k_gemm(const u16* __restrict__ A,
                                                 const u16* __restrict__ Bt,
                                                 void* __restrict__ Cout,
                                                 int M, int Nt, int K) {
  __shared__ u16 As[128 * 32];
  __shared__ u16 Bs[128 * 32];
  const int tid = threadIdx.x, lane = tid & 63, wid = tid >> 6;
  const int m0 = blockIdx.y * 128, n0 = blockIdx.x * 128;
  const int wm = (wid >> 1) * 64, wn = (wid & 1) * 64;
  const int fr = lane & 15, fc = (lane >> 4) * 8;

  f32x4 acc[4][4] = {};

  // staging: wave wid covers rows [wid*32, wid*32+32), 2 insts of 1KB each
  const u16* gA = A + (size_t)(m0 + wid * 32 + (lane >> 2)) * K + (lane & 3) * 8;
  const u16* gB = Bt + (size_t)(n0 + wid * 32 + (lane >> 2)) * K + (lane & 3) * 8;
  u16* lA = As + wid * 1024;
  u16* lB = Bs + wid * 1024;
  const size_t rowskip = (size_t)16 * K;

  for (int k0 = 0; k0 < K; k0 += 32) {
    gload_lds16(gA + k0, lA);
    gload_lds16(gA + k0 + rowskip, lA + 512);
    gload_lds16(gB + k0, lB);
    gload_lds16(gB + k0 + rowskip, lB + 512);
    __syncthreads();
    u16x8 a[4], b[4];
#pragma unroll
    for (int mi = 0; mi < 4; mi++) a[mi] = *(const u16x8*)(As + (wm + mi * 16 + fr) * 32 + fc);
#pragma unroll
    for (int ni = 0; ni < 4; ni++) b[ni] = *(const u16x8*)(Bs + (wn + ni * 16 + fr) * 32 + fc);
#pragma unroll
    for (int mi = 0; mi < 4; mi++)
#pragma unroll
      for (int ni = 0; ni < 4; ni++)
        acc[mi][ni] = mfma16(a[mi], b[ni], acc[mi][ni]);
    __syncthreads();
  }

  const int frow = (lane >> 4) * 4;
#pragma unroll
  for (int mi = 0; mi < 4; mi++)
#pragma unroll
    for (int ni = 0; ni < 4; ni++)
#pragma unroll
      for (int j = 0; j < 4; j++) {
        const size_t row = m0 + wm + mi * 16 + frow + j;
        const size_t col = n0 + wn + ni * 16 + fr;
        if (F32OUT) ((float*)Cout)[row * Nt + col] = acc[mi][ni][j];
        else ((u16*)Cout)[row * Nt + col] = f2bf(acc[mi][ni][j]);
      }
}

// ---------------- normalize: qg/kv raw -> qn, kn, vnT, gact ----------------
// block = (64-n chunk, hb). 4 waves; each wave handles 16 n values serially.
// vnT transposed through a swizzled LDS tile so global writes are 128B-contiguous.
__global__ __launch_bounds__(256, 4) void k_norm(const u16* __restrict__ qg,
                                                 const u16* __restrict__ kv,
                                                 u16* __restrict__ qn, u16* __restrict__ kn,
                                                 u16* __restrict__ vnT, u16* __restrict__ gact) {
  __shared__ u16 vt[128 * 64];  // [d][nl], col swizzle: c' = nl ^ ((d&15)<<2)
  const int tid = threadIdx.x, lane = tid & 63, wid = tid >> 6;
  const int hb = blockIdx.y;            // b*16 + h
  const int h = hb & 15, b = hb >> 4;
  const int n0 = blockIdx.x * 64;

  for (int s = 0; s < 16; s++) {
    const int nl = wid * 16 + s;        // 0..63
    const int n = n0 + nl;
    const size_t bn = (size_t)b * 2048 + n;
    const size_t base = bn * 3072 + (size_t)h * 192;

    float q = bf2f(qg[base + lane]);
    float g0 = bf2f(qg[base + 64 + lane]);
    float g1 = bf2f(qg[base + 128 + lane]);
    float k = bf2f(kv[base + lane]);
    float v0 = bf2f(kv[base + 64 + lane]);
    float v1 = bf2f(kv[base + 128 + lane]);

    float qs = q * q, ks = k * k, vs = v0 * v0 + v1 * v1;
#pragma unroll
    for (int m = 1; m < 64; m <<= 1) {
      qs += __shfl_xor(qs, m);
      ks += __shfl_xor(ks, m);
      vs += __shfl_xor(vs, m);
    }
    float rq = 1.f / fmaxf(sqrtf(qs), 1e-12f);
    float rk = 1.f / fmaxf(sqrtf(ks), 1e-12f);
    float rv = 1.f / fmaxf(sqrtf(vs), 1e-12f);

    qn[((size_t)hb * 2048 + n) * 64 + lane] = f2bf(q * rq);
    kn[((size_t)hb * 2048 + n) * 64 + lane] = f2bf(k * rk);
    float s0 = g0 / (1.f + __expf(-g0));
    float s1 = g1 / (1.f + __expf(-g1));
    gact[((size_t)hb * 2048 + n) * 128 + lane] = f2bf(tanhf(s0));
    gact[((size_t)hb * 2048 + n) * 128 + 64 + lane] = f2bf(tanhf(s1));

    const int d0 = lane, d1 = 64 + lane;
    vt[d0 * 64 + (nl ^ ((d0 & 15) << 2))] = f2bf(v0 * rv);
    vt[d1 * 64 + (nl ^ ((d1 & 15) << 2))] = f2bf(v1 * rv);
  }
  __syncthreads();

  // write-out: 8 passes, 16 lanes per d-row write 4 n each (128B contiguous)
#pragma unroll
  for (int p = 0; p < 8; p++) {
    const int d = p * 16 + (tid >> 4);
    const int nq = (tid & 15) * 4;
    const int cb = nq ^ ((d & 15) << 2);
    ushort4 o;
    o.x = vt[d * 64 + cb + 0];
    o.y = vt[d * 64 + cb + 1];
    o.z = vt[d * 64 + cb + 2];
    o.w = vt[d * 64 + cb + 3];
    *(ushort4*)(vnT + ((size_t)hb * 128 + d) * 2048 + n0 + nq) = o;
  }
}

// ---------------- fused screened attention ----------------
// grid (N/128, B*H), 256 threads (4 waves). Q in regs; K,V double-buffered in LDS,
// P in LDS; all XOR-swizzled. 2-phase pipeline with EXPLICIT waitcnt + raw s_barrier
// (R4 raced relying on __syncthreads' implicit vmcnt drain across the backedge):
//   B1: s_waitcnt vmcnt(0) lgkmcnt(0); s_barrier     -- staged buf[cur] ready
//   STAGE(t+1) -> buf[cur^1]   (in flight across B2, drained at next B1)
//   QK^T(t); P-write
//   B2: s_waitcnt lgkmcnt(0); s_barrier               -- P visible; vmcnt untouched
//   PV(t)
// Hazards: stage writes buf[c^1]; its prior readers (QK/PV of t-1) retired before
// B1(t) (lgkmcnt(0) + MFMA reg deps). P-write(t+1) vs PV-read(t) split by B1(t+1).
// LDS = 2*8K(Ks) + 2*16K(Vs) + 16K(Ps) = 64KB -> 2 blocks/CU (grid 512 = 2/CU exact).
__global__ __launch_bounds__(256, 2) void k_attn(const u16* __restrict__ qn,
                                                 const u16* __restrict__ kn,
                                                 const u16* __restrict__ vnT,
                                                 const u16* __restrict__ gact,
                                                 const float* __restrict__ ls_iaw,
                                                 const float* __restrict__ ls_hws,
                                                 u16* __restrict__ pre_out) {
  extern __shared__ char smem[];
  u16* KsB = (u16*)smem;                 // [2][64 k][64 dk]  8KB each
  u16* VsB = (u16*)(smem + 16384);       // [2][128 d][64 k]  16KB each
  u16* Ps = (u16*)(smem + 49152);        // [128 q][64 k]     16KB
  float* nbuf = (float*)(smem + 49152);  // reuse after loop: [2][128]

  const int tid = threadIdx.x, lane = tid & 63, wid = tid >> 6;
  const int bh = blockIdx.y, h = bh & 15;
  const int n0 = blockIdx.x * 128;
  const int wq = (wid >> 1) * 64;
  const int wckv = (wid & 1) * 32;   // QK: this wave's kv-half (32 wide)
  const int wcd = (wid & 1) * 64;    // PV: this wave's d-half (64 wide)
  const float r = 1.f / (__expf(ls_iaw[h]) + 1.f);
  const float whs = __expf(ls_hws[h]);
  const int fr = lane & 15, hi = lane >> 4, fc = hi * 8, frow = hi * 4;
  const int rb = fr & 7;

  // Q fragments in registers (reused across all KV tiles)
  const u16* qbase = qn + ((size_t)bh * 2048 + n0) * 64;
  u16x8 qf[4][2];
#pragma unroll
  for (int mi = 0; mi < 4; mi++)
#pragma unroll
    for (int kk = 0; kk < 2; kk++)
      qf[mi][kk] = *(const u16x8*)(qbase + (wq + mi * 16 + fr) * 64 + kk * 32 + fc);

  f32x4 acc[4][4] = {};
  const u16* kbase = kn + (size_t)bh * 2048 * 64;
  const u16* vbase = vnT + (size_t)bh * 128 * 2048;

  // staging per-lane constants (inverse-swizzled global offsets, u16 units)
  int ks_goff[2];   // K: 2 x 1KB insts/wave; row = wid*16 + i*8 + (lane>>3)
#pragma unroll
  for (int i = 0; i < 2; i++) {
    int row = wid * 16 + i * 8 + (lane >> 3);
    ks_goff[i] = row * 64 + (((lane & 7) ^ (row & 7)) << 3);
  }
  int vs_goff[4];   // V: 4 x 1KB insts/wave; row = wid*32 + i*8 + (lane>>3)
#pragma unroll
  for (int i = 0; i < 4; i++) {
    int row = wid * 32 + i * 8 + (lane >> 3);
    vs_goff[i] = row * 2048 + (((lane & 7) ^ (row & 7)) << 3);
  }

  // prologue: stage tile 0 into buffer 0
  {
    u16* KsC = KsB + wid * 1024;
    u16* VsC = VsB + wid * 2048;
#pragma unroll
    for (int i = 0; i < 2; i++) gload_lds16(kbase + ks_goff[i], KsC + i * 512);
#pragma unroll
    for (int i = 0; i < 4; i++) gload_lds16(vbase + vs_goff[i], VsC + i * 512);
  }

  int cur = 0;
  for (int t = 0; t < 32; t++) {
    // B1: my staged loads retired (explicit), everyone's retired (barrier)
    asm volatile("s_waitcnt vmcnt(0) lgkmcnt(0)" ::: "memory");
    __builtin_amdgcn_s_barrier();
    asm volatile("" ::: "memory");

    // issue next tile's staging immediately: in flight across QK, P, B2, PV.
    // buf[cur^1]'s last readers (QK/PV of t-1) retired before B1 above.
    if (t < 31) {
      const int kv0 = (t + 1) * 64;
      u16* KsC2 = KsB + (cur ^ 1) * 4096 + wid * 1024;
      u16* VsC2 = VsB + (cur ^ 1) * 8192 + wid * 2048;
#pragma unroll
      for (int i = 0; i < 2; i++) gload_lds16(kbase + (size_t)kv0 * 64 + ks_goff[i], KsC2 + i * 512);
#pragma unroll
      for (int i = 0; i < 4; i++) gload_lds16(vbase + (size_t)vs_goff[i] + kv0, VsC2 + i * 512);
    }

    const u16* KsC = KsB + cur * 4096;
    // sim = q @ k^T for this wave's (wq, wckv)
    f32x4 s[4][2] = {};
    __builtin_amdgcn_s_setprio(1);
#pragma unroll
    for (int kk = 0; kk < 2; kk++) {
      u16x8 kf[2];
#pragma unroll
      for (int ni = 0; ni < 2; ni++) {
        const int row = wckv + ni * 16 + fr;
        kf[ni] = *(const u16x8*)(KsC + row * 64 + (((kk * 4 + hi) ^ rb) << 3));
      }
#pragma unroll
      for (int mi = 0; mi < 4; mi++)
#pragma unroll
        for (int ni = 0; ni < 2; ni++)
          s[mi][ni] = mfma16(qf[mi][kk], kf[ni], s[mi][ni]);
    }
    __builtin_amdgcn_s_setprio(0);

    // screen + write P to LDS (swizzled)
#pragma unroll
    for (int mi = 0; mi < 4; mi++)
#pragma unroll
      for (int ni = 0; ni < 2; ni++)
#pragma unroll
        for (int j = 0; j < 4; j++) {
          const int row = wq + mi * 16 + frow + j;
          const int col = wckv + ni * 16 + fr;
          float p = fmaxf(0.f, 1.f - r * (1.f - s[mi][ni][j]));
          Ps[row * 64 + (col ^ ((row & 7) << 3))] = f2bf(p * p);
        }

    // B2: P visible to all; do NOT drain vmcnt (stage stays in flight)
    asm volatile("s_waitcnt lgkmcnt(0)" ::: "memory");
    __builtin_amdgcn_s_barrier();
    asm volatile("" ::: "memory");

    // PV: acc += P @ V  (wcd = this wave's d-half)
    const u16* VsC = VsB + cur * 8192;
    __builtin_amdgcn_s_setprio(1);
#pragma unroll
    for (int kk = 0; kk < 2; kk++) {
      u16x8 pf[4], vf[4];
#pragma unroll
      for (int mi = 0; mi < 4; mi++) {
        const int row = wq + mi * 16 + fr;
        pf[mi] = *(const u16x8*)(Ps + row * 64 + (((kk * 4 + hi) ^ rb) << 3));
      }
#pragma unroll
      for (int ni = 0; ni < 4; ni++) {
        const int row = wcd + ni * 16 + fr;
        vf[ni] = *(const u16x8*)(VsC + row * 64 + (((kk * 4 + hi) ^ rb) << 3));
      }
#pragma unroll
      for (int mi = 0; mi < 4; mi++)
#pragma unroll
        for (int ni = 0; ni < 4; ni++)
          acc[mi][ni] = mfma16(pf[mi], vf[ni], acc[mi][ni]);
    }
    __builtin_amdgcn_s_setprio(0);
    cur ^= 1;
  }
  __syncthreads();  // full drain (vmcnt=0 at exit); all PV done before nbuf overwrite

  // epilogue: tanh_norm(aggr) * gact * exp(ls_hws) -> pre_out[(b*N+n)][h*128+d]
#pragma unroll
  for (int mi = 0; mi < 4; mi++)
#pragma unroll
    for (int j = 0; j < 4; j++) {
      float ss = 0.f;
#pragma unroll
      for (int ni = 0; ni < 4; ni++) { float x = acc[mi][ni][j]; ss += x * x; }
#pragma unroll
      for (int m = 1; m < 16; m <<= 1) ss += __shfl_xor(ss, m);
      if (fr == 0) nbuf[(wid & 1) * 128 + wq + mi * 16 + frow + j] = ss;
    }
  __syncthreads();

  const size_t gbase = ((size_t)bh * 2048 + n0) * 128;
  const size_t obase = ((size_t)(bh >> 4) * 2048 + n0);
#pragma unroll
  for (int mi = 0; mi < 4; mi++)
#pragma unroll
    for (int j = 0; j < 4; j++) {
      const int row = wq + mi * 16 + frow + j;
      float nsq = nbuf[row] + nbuf[128 + row];
      float nn = sqrtf(nsq);
      float scale = tanhf(nn) / fmaxf(nn, 1e-12f) * whs;
#pragma unroll
      for (int ni = 0; ni < 4; ni++) {
        const int d = wcd + ni * 16 + fr;
        float gv = bf2f(gact[gbase + (size_t)row * 128 + d]);
        pre_out[(obase + row) * 2048 + h * 128 + d] = f2bf(acc[mi][ni][j] * scale * gv);
      }
    }
}

extern "C" void kernel_launch(void* const* d_in, const int* in_sizes, int n_in,
                              void* d_out, int out_size, void* d_ws, size_t ws_size,
                              hipStream_t stream) {
  (void)in_sizes; (void)n_in; (void)out_size; (void)ws_size;
  const float* tokens = (const float*)d_in[0];
  const float* Wqg = (const float*)d_in[1];
  const float* Wkv = (const float*)d_in[2];
  const float* Wo = (const float*)d_in[3];
  const float* ls_iaw = (const float*)d_in[4];
  const float* ls_hws = (const float*)d_in[5];
  float* out = (float*)d_out;
  char* ws = (char*)d_ws;

  // workspace layout (phased aliasing, total 104 MB):
  u16* WoT = (u16*)(ws + 0);                     // 8,388,608 B
  char* regA = ws + 8388608;                     // 50,331,648 B
  u16* tok_bf = (u16*)(regA);                    // phase A-B
  u16* WqgT = (u16*)(regA + 16777216);
  u16* WkvT = (u16*)(regA + 29360128);
  u16* qn = (u16*)(regA);                        // phase C-D
  u16* kn = (u16*)(regA + 8388608);
  u16* vnT = (u16*)(regA + 16777216);
  u16* gact = (u16*)(regA + 33554432);
  char* regB = ws + 58720256;                    // 50,331,648 B
  u16* qg_raw = (u16*)(regB);                    // phase B-C
  u16* kv_raw = (u16*)(regB + 25165824);
  u16* pre_out = (u16*)(regB);                   // phase D-E

  k_cvt<<<4096, 256, 0, stream>>>(tokens, tok_bf, 8388608);
  k_cvtT<<<dim3(96, 64), 256, 0, stream>>>(Wqg, WqgT, 2048, 3072);
  k_cvtT<<<dim3(96, 64), 256, 0, stream>>>(Wkv, WkvT, 2048, 3072);
  k_cvtT<<<dim3(64, 64), 256, 0, stream>>>(Wo, WoT, 2048, 2048);

  k_gemm<0><<<dim3(24, 32), 256, 0, stream>>>(tok_bf, WqgT, qg_raw, 4096, 3072, 2048);
  k_gemm<0><<<dim3(24, 32), 256, 0, stream>>>(tok_bf, WkvT, kv_raw, 4096, 3072, 2048);

  k_norm<<<dim3(32, 32), 256, 0, stream>>>(qg_raw, kv_raw, qn, kn, vnT, gact);

  k_attn<<<dim3(16, 32), 256, 65536, stream>>>(qn, kn, vnT, gact, ls_iaw, ls_hws, pre_out);

  k_gemm<1><<<dim3(16, 32), 256, 0, stream>>>(pre_out, WoT, out, 4096, 2048, 2048);
}

// Round 7
// 302.147 us; speedup vs baseline: 2.2060x; 1.0247x over previous
//
#include <hip/hip_runtime.h>
#include <hip/hip_bf16.h>
#include <stdint.h>

// GatedScreeningTile: B=2 N=2048 DIM=2048 H=16 DK=64 DV=128 DIM_INNER=3072
// Pipeline: cvt/transpose -> merged GEMM(qg|kv) -> normalize -> fused screened-attention -> GEMM(out)

typedef unsigned short u16;
typedef __bf16 bf16x8 __attribute__((ext_vector_type(8)));
typedef u16 u16x8 __attribute__((ext_vector_type(8)));
typedef float f32x4 __attribute__((ext_vector_type(4)));
typedef float f32x16 __attribute__((ext_vector_type(16)));
typedef int i32x4 __attribute__((ext_vector_type(4)));

#define DEVINL __device__ __forceinline__

DEVINL u16 f2bf(float f) {
  union { float f; uint32_t u; } v; v.f = f;
  uint32_t r = (v.u + 0x7FFFu + ((v.u >> 16) & 1u)) >> 16;
  return (u16)r;
}
DEVINL float bf2f(u16 x) {
  union { uint32_t u; float f; } v; v.u = ((uint32_t)x) << 16;
  return v.f;
}
DEVINL bf16x8 as_bf(u16x8 v) { return __builtin_bit_cast(bf16x8, v); }

typedef const __attribute__((address_space(1))) uint32_t* gptr_t;
typedef __attribute__((address_space(3))) uint32_t* lptr_t;
DEVINL void gload_lds16(const void* g, void* l) {
  __builtin_amdgcn_global_load_lds((gptr_t)g, (lptr_t)l, 16, 0, 0);
}

DEVINL f32x4 mfma16(u16x8 a, u16x8 b, f32x4 c) {
  return __builtin_amdgcn_mfma_f32_16x16x32_bf16(as_bf(a), as_bf(b), c, 0, 0, 0);
}
DEVINL f32x16 mfma32(u16x8 a, u16x8 b, f32x16 c) {
  return __builtin_amdgcn_mfma_f32_32x32x16_bf16(as_bf(a), as_bf(b), c, 0, 0, 0);
}

// ---------------- fp32 -> bf16 convert (same layout) ----------------
__global__ void k_cvt(const float* __restrict__ src, u16* __restrict__ dst, int n) {
  int i = (blockIdx.x * blockDim.x + threadIdx.x) * 4;
  int stride = gridDim.x * blockDim.x * 4;
  for (; i < n; i += stride) {
    float4 f = *(const float4*)(src + i);
    ushort4 o;
    o.x = f2bf(f.x); o.y = f2bf(f.y); o.z = f2bf(f.z); o.w = f2bf(f.w);
    *(ushort4*)(dst + i) = o;
  }
}

// ---------------- fp32 (RxC) -> bf16 transposed (CxR) ----------------
__global__ void k_cvtT(const float* __restrict__ src, u16* __restrict__ dst, int R, int C) {
  __shared__ float tile[32][33];
  int c0 = blockIdx.x * 32, r0 = blockIdx.y * 32;
  int tc = threadIdx.x & 31, tr = threadIdx.x >> 5;  // tr 0..7
#pragma unroll
  for (int i = 0; i < 4; i++) {
    int r = tr + i * 8;
    tile[r][tc] = src[(size_t)(r0 + r) * C + c0 + tc];
  }
  __syncthreads();
#pragma unroll
  for (int i = 0; i < 4; i++) {
    int r = tr + i * 8;  // row in dst tile (= src col)
    dst[(size_t)(c0 + r) * R + r0 + tc] = f2bf(tile[tc][r]);
  }
}

// ---------------- bf16 GEMM: C(MxNt) = A(MxK,row-major) * Bt(NtxK,row-major)^T ----------------
// 128x128 tile, BK=32, 4 waves (2x2), 16x16x32 MFMA, global_load_lds staging.
template <int F32OUT>
__global__ __launch_bounds__(256, 2) void k_gemm(const u16* __restrict__ A,
                                                 const u16* __restrict__ Bt,
                                                 void* __restrict__ Cout,
                                                 int M, int Nt, int K) {
  __shared__ u16 As[128 * 32];
  __shared__ u16 Bs[128 * 32];
  const int tid = threadIdx.x, lane = tid & 63, wid = tid >> 6;
  const int m0 = blockIdx.y * 128, n0 = blockIdx.x * 128;
  const int wm = (wid >> 1) * 64, wn = (wid & 1) * 64;
  const int fr = lane & 15, fc = (lane >> 4) * 8;

  f32x4 acc[4][4] = {};

  const u16* gA = A + (size_t)(m0 + wid * 32 + (lane >> 2)) * K + (lane & 3) * 8;
  const u16* gB = Bt + (size_t)(n0 + wid * 32 + (lane >> 2)) * K + (lane & 3) * 8;
  u16* lA = As + wid * 1024;
  u16* lB = Bs + wid * 1024;
  const size_t rowskip = (size_t)16 * K;

  for (int k0 = 0; k0 < K; k0 += 32) {
    gload_lds16(gA + k0, lA);
    gload_lds16(gA + k0 + rowskip, lA + 512);
    gload_lds16(gB + k0, lB);
    gload_lds16(gB + k0 + rowskip, lB + 512);
    __syncthreads();
    u16x8 a[4], b[4];
#pragma unroll
    for (int mi = 0; mi < 4; mi++) a[mi] = *(const u16x8*)(As + (wm + mi * 16 + fr) * 32 + fc);
#pragma unroll
    for (int ni = 0; ni < 4; ni++) b[ni] = *(const u16x8*)(Bs + (wn + ni * 16 + fr) * 32 + fc);
#pragma unroll
    for (int mi = 0; mi < 4; mi++)
#pragma unroll
      for (int ni = 0; ni < 4; ni++)
        acc[mi][ni] = mfma16(a[mi], b[ni], acc[mi][ni]);
    __syncthreads();
  }

  const int frow = (lane >> 4) * 4;
#pragma unroll
  for (int mi = 0; mi < 4; mi++)
#pragma unroll
    for (int ni = 0; ni < 4; ni++)
#pragma unroll
      for (int j = 0; j < 4; j++) {
        const size_t row = m0 + wm + mi * 16 + frow + j;
        const size_t col = n0 + wn + ni * 16 + fr;
        if (F32OUT) ((float*)Cout)[row * Nt + col] = acc[mi][ni][j];
        else ((u16*)Cout)[row * Nt + col] = f2bf(acc[mi][ni][j]);
      }
}

// ---------------- normalize: qgkv raw -> qn, kn, vnT, gact ----------------
// vnT stored with sigma-permuted columns within each 32-n group (swap bits 2,3)
// so that attn's PV A-fragment k-order matches the in-register P^T B-fragment.
__global__ __launch_bounds__(256, 4) void k_norm(const u16* __restrict__ qgkv,
                                                 u16* __restrict__ qn, u16* __restrict__ kn,
                                                 u16* __restrict__ vnT, u16* __restrict__ gact) {
  __shared__ u16 vt[128 * 64];  // [d][nl], col swizzle: c' = nl ^ ((d&15)<<2)
  const int tid = threadIdx.x, lane = tid & 63, wid = tid >> 6;
  const int hb = blockIdx.y;            // b*16 + h
  const int h = hb & 15, b = hb >> 4;
  const int n0 = blockIdx.x * 64;

  for (int s = 0; s < 16; s++) {
    const int nl = wid * 16 + s;        // 0..63
    const int n = n0 + nl;
    const size_t bn = (size_t)b * 2048 + n;
    const size_t baseq = bn * 6144 + (size_t)h * 192;
    const size_t basek = baseq + 3072;

    float q = bf2f(qgkv[baseq + lane]);
    float g0 = bf2f(qgkv[baseq + 64 + lane]);
    float g1 = bf2f(qgkv[baseq + 128 + lane]);
    float k = bf2f(qgkv[basek + lane]);
    float v0 = bf2f(qgkv[basek + 64 + lane]);
    float v1 = bf2f(qgkv[basek + 128 + lane]);

    float qs = q * q, ks = k * k, vs = v0 * v0 + v1 * v1;
#pragma unroll
    for (int m = 1; m < 64; m <<= 1) {
      qs += __shfl_xor(qs, m);
      ks += __shfl_xor(ks, m);
      vs += __shfl_xor(vs, m);
    }
    float rq = 1.f / fmaxf(sqrtf(qs), 1e-12f);
    float rk = 1.f / fmaxf(sqrtf(ks), 1e-12f);
    float rv = 1.f / fmaxf(sqrtf(vs), 1e-12f);

    qn[((size_t)hb * 2048 + n) * 64 + lane] = f2bf(q * rq);
    kn[((size_t)hb * 2048 + n) * 64 + lane] = f2bf(k * rk);
    float s0 = g0 / (1.f + __expf(-g0));
    float s1 = g1 / (1.f + __expf(-g1));
    gact[((size_t)hb * 2048 + n) * 128 + lane] = f2bf(tanhf(s0));
    gact[((size_t)hb * 2048 + n) * 128 + 64 + lane] = f2bf(tanhf(s1));

    const int d0 = lane, d1 = 64 + lane;
    vt[d0 * 64 + (nl ^ ((d0 & 15) << 2))] = f2bf(v0 * rv);
    vt[d1 * 64 + (nl ^ ((d1 & 15) << 2))] = f2bf(v1 * rv);
  }
  __syncthreads();

  // write-out: sigma(col) = swap bits 2<->3 within n&31 (preserves bits 0-1)
#pragma unroll
  for (int p = 0; p < 8; p++) {
    const int d = p * 16 + (tid >> 4);
    const int nq = (tid & 15) * 4;
    const int cb = nq ^ ((d & 15) << 2);
    const int nq2 = (nq & ~12) | ((nq & 4) << 1) | ((nq & 8) >> 1);
    ushort4 o;
    o.x = vt[d * 64 + cb + 0];
    o.y = vt[d * 64 + cb + 1];
    o.z = vt[d * 64 + cb + 2];
    o.w = vt[d * 64 + cb + 3];
    *(ushort4*)(vnT + ((size_t)hb * 128 + d) * 2048 + n0 + nq2) = o;
  }
}

// ---------------- fused screened attention (swapped-operand 32x32, P in registers) ----------------
// grid (16,32) remapped XCD-aware; 256 threads = 4 waves, each owns a 32-q tile fully.
// Per KV tile (64): QK^T swapped: sT = mfma32(A=K, B=Q) -> lane holds P^T[k][q=lane&31];
// screen elementwise in regs; PV: acc^T[d][q] = mfma32(A=V^T, B=P^T) where the P^T
// B-frag is 4 OWN registers (k-grouping (m,m+1) pairs; V's matching k-order comes from
// vnT's sigma column permutation). ONE barrier per tile; K,V double-buffered (48KB LDS).
__global__ __launch_bounds__(256, 2) void k_attn(const u16* __restrict__ qn,
                                                 const u16* __restrict__ kn,
                                                 const u16* __restrict__ vnT,
                                                 const u16* __restrict__ gact,
                                                 const float* __restrict__ ls_iaw,
                                                 const float* __restrict__ ls_hws,
                                                 u16* __restrict__ pre_out) {
  extern __shared__ char smem[];
  u16* KsB = (u16*)smem;                 // [2][64 k][64 dk]  8KB each
  u16* VsB = (u16*)(smem + 16384);       // [2][128 d][64 k'] 16KB each (k' sigma-order)
  u16* Os = (u16*)smem;                  // epilogue reuse: [128 q][132 d] 33.8KB

  const int tid = threadIdx.x, lane = tid & 63, wid = tid >> 6;
  // XCD-aware remap: same-bh blocks cluster on one XCD (K/V fits 4MB L2)
  const int bid = blockIdx.y * 16 + blockIdx.x;
  const int bh = (bid & 7) * 4 + ((bid >> 3) & 3);
  const int n0 = (bid >> 5) * 128;
  const int h = bh & 15;
  const int l31 = lane & 31, L = lane >> 5, rb = l31 & 7;
  const float r = 1.f / (__expf(ls_iaw[h]) + 1.f);
  const float c1 = 1.f - r;
  const float whs = __expf(ls_hws[h]);

  // Q fragments (B-operand): lane holds Q[q = wq + l31][dk = 16c + 8L .. +7]
  const int wq = wid * 32;
  const u16* qrow = qn + ((size_t)bh * 2048 + n0 + wq + l31) * 64;
  u16x8 qf[4];
#pragma unroll
  for (int c = 0; c < 4; c++) qf[c] = *(const u16x8*)(qrow + c * 16 + L * 8);

  f32x16 acc[4] = {};  // acc[dt]: D[d = dt*32 + (reg&3)+8*(reg>>2)+4L][q = l31]
  const u16* kbase = kn + (size_t)bh * 2048 * 64;
  const u16* vbase = vnT + (size_t)bh * 128 * 2048;

  // staging per-lane constants (inverse bank-swizzle on global source)
  int ks_goff[2];
#pragma unroll
  for (int i = 0; i < 2; i++) {
    int row = wid * 16 + i * 8 + (lane >> 3);
    ks_goff[i] = row * 64 + (((lane & 7) ^ (row & 7)) << 3);
  }
  int vs_goff[4];
#pragma unroll
  for (int i = 0; i < 4; i++) {
    int row = wid * 32 + i * 8 + (lane >> 3);
    vs_goff[i] = row * 2048 + (((lane & 7) ^ (row & 7)) << 3);
  }

  // prologue: stage tile 0 into buffer 0
  {
    u16* KsC = KsB + wid * 1024;
    u16* VsC = VsB + wid * 2048;
#pragma unroll
    for (int i = 0; i < 2; i++) gload_lds16(kbase + ks_goff[i], KsC + i * 512);
#pragma unroll
    for (int i = 0; i < 4; i++) gload_lds16(vbase + vs_goff[i], VsC + i * 512);
  }

  int cur = 0;
  for (int t = 0; t < 32; t++) {
    // B1: staged buf[cur] landed everywhere; my prior ds_reads retired.
    asm volatile("s_waitcnt vmcnt(0) lgkmcnt(0)" ::: "memory");
    __builtin_amdgcn_s_barrier();
    asm volatile("" ::: "memory");

    // stage(t+1) -> buf^1: in flight across the whole iteration.
    if (t < 31) {
      const int kv0 = (t + 1) * 64;
      u16* KsC2 = KsB + (cur ^ 1) * 4096 + wid * 1024;
      u16* VsC2 = VsB + (cur ^ 1) * 8192 + wid * 2048;
#pragma unroll
      for (int i = 0; i < 2; i++) gload_lds16(kbase + (size_t)kv0 * 64 + ks_goff[i], KsC2 + i * 512);
#pragma unroll
      for (int i = 0; i < 4; i++) gload_lds16(vbase + (size_t)vs_goff[i] + kv0, VsC2 + i * 512);
    }

    const u16* KsC = KsB + cur * 4096;
    const u16* VsC = VsB + cur * 8192;

    // QK^T swapped: sT[kt] = S^T[k = 32kt + 8(reg>>2) + 4L + (reg&3)][q = l31]
    f32x16 sT0 = {}, sT1 = {};
    __builtin_amdgcn_s_setprio(1);
#pragma unroll
    for (int c = 0; c < 4; c++) {
      u16x8 kf0 = *(const u16x8*)(KsC + (0 + l31) * 64 + (((2 * c + L) ^ rb) << 3));
      u16x8 kf1 = *(const u16x8*)(KsC + (32 + l31) * 64 + (((2 * c + L) ^ rb) << 3));
      sT0 = mfma32(kf0, qf[c], sT0);
      sT1 = mfma32(kf1, qf[c], sT1);
    }
    __builtin_amdgcn_s_setprio(0);

    // screen elementwise + pack to bf16 pairs: w[kt][m][p] holds k = 32kt+8m+4L+2p+{0,1}
    uint32_t w[2][4][2];
#pragma unroll
    for (int m = 0; m < 4; m++)
#pragma unroll
      for (int p = 0; p < 2; p++) {
        float a0 = fmaxf(0.f, fmaf(r, sT0[4 * m + 2 * p], c1));
        float a1 = fmaxf(0.f, fmaf(r, sT0[4 * m + 2 * p + 1], c1));
        float b0 = fmaxf(0.f, fmaf(r, sT1[4 * m + 2 * p], c1));
        float b1 = fmaxf(0.f, fmaf(r, sT1[4 * m + 2 * p + 1], c1));
        w[0][m][p] = (uint32_t)f2bf(a0 * a0) | ((uint32_t)f2bf(a1 * a1) << 16);
        w[1][m][p] = (uint32_t)f2bf(b0 * b0) | ((uint32_t)f2bf(b1 * b1) << 16);
      }

    // PV: acc[dt] += mfma32(A=V^T-frag, B=P^T-frag); B-frag = 4 own registers.
    __builtin_amdgcn_s_setprio(1);
#pragma unroll
    for (int kt = 0; kt < 2; kt++)
#pragma unroll
      for (int pair = 0; pair < 2; pair++) {
        i32x4 pw;
        pw[0] = (int)w[kt][2 * pair][0];
        pw[1] = (int)w[kt][2 * pair][1];
        pw[2] = (int)w[kt][2 * pair + 1][0];
        pw[3] = (int)w[kt][2 * pair + 1][1];
        u16x8 pf = __builtin_bit_cast(u16x8, pw);
        const int chunk = 4 * kt + 2 * pair + L;
#pragma unroll
        for (int dt = 0; dt < 4; dt++) {
          u16x8 vf = *(const u16x8*)(VsC + (dt * 32 + l31) * 64 + ((chunk ^ rb) << 3));
          acc[dt] = mfma32(vf, pf, acc[dt]);
        }
      }
    __builtin_amdgcn_s_setprio(0);
    cur ^= 1;
  }

  // epilogue: lane owns q = wq + l31 (its column); d spread over (dt, reg, L).
  float ss = 0.f;
#pragma unroll
  for (int dt = 0; dt < 4; dt++)
#pragma unroll
    for (int e = 0; e < 16; e++) { float x = acc[dt][e]; ss += x * x; }
  ss += __shfl_xor(ss, 32);  // partner L-half has the other d values for same q
  float nn = sqrtf(ss);
  float scale = tanhf(nn) / fmaxf(nn, 1e-12f) * whs;

  __syncthreads();  // all waves done with KsB/VsB before Os overwrite

  const int q = wq + l31;
  const size_t grow = ((size_t)bh * 2048 + n0 + q) * 128;
#pragma unroll
  for (int dt = 0; dt < 4; dt++)
#pragma unroll
    for (int m = 0; m < 4; m++) {
      const int d = dt * 32 + 8 * m + 4 * L;
      ushort4 gv = *(const ushort4*)(gact + grow + d);
      ushort4 o;
      o.x = f2bf(acc[dt][4 * m + 0] * scale * bf2f(gv.x));
      o.y = f2bf(acc[dt][4 * m + 1] * scale * bf2f(gv.y));
      o.z = f2bf(acc[dt][4 * m + 2] * scale * bf2f(gv.z));
      o.w = f2bf(acc[dt][4 * m + 3] * scale * bf2f(gv.w));
      *(ushort4*)(Os + q * 132 + d) = o;  // 8B-aligned (264B rows); padding breaks bank alignment
    }
  __syncthreads();

  // write-out: thread -> (row = tid>>1, 64-u16 half = (tid&1)*64): covers ALL 128 rows.
  // 16 x ushort4 (8B-aligned) per thread = 128B contiguous global store per thread.
  const int orow = tid >> 1, oc0 = (tid & 1) * 64;
  const size_t obase = ((size_t)(bh >> 4) * 2048 + n0 + orow) * 2048 + (size_t)h * 128 + oc0;
#pragma unroll
  for (int j = 0; j < 16; j++) {
    ushort4 v = *(const ushort4*)(Os + orow * 132 + oc0 + 4 * j);
    *(ushort4*)(pre_out + obase + 4 * j) = v;
  }
}

extern "C" void kernel_launch(void* const* d_in, const int* in_sizes, int n_in,
                              void* d_out, int out_size, void* d_ws, size_t ws_size,
                              hipStream_t stream) {
  (void)in_sizes; (void)n_in; (void)out_size; (void)ws_size;
  const float* tokens = (const float*)d_in[0];
  const float* Wqg = (const float*)d_in[1];
  const float* Wkv = (const float*)d_in[2];
  const float* Wo = (const float*)d_in[3];
  const float* ls_iaw = (const float*)d_in[4];
  const float* ls_hws = (const float*)d_in[5];
  float* out = (float*)d_out;
  char* ws = (char*)d_ws;

  // workspace layout (phased aliasing, total 109 MB):
  u16* WoT = (u16*)(ws + 0);                     // 8,388,608 B
  char* regA = ws + 8388608;                     // 50,331,648 B
  u16* tok_bf = (u16*)(regA);                    // phase A-B (16.8MB)
  u16* WqgkvT = (u16*)(regA + 16777216);         // phase A-B (25.2MB) [6144][2048]
  u16* qn = (u16*)(regA);                        // phase C-D
  u16* kn = (u16*)(regA + 8388608);
  u16* vnT = (u16*)(regA + 16777216);
  u16* gact = (u16*)(regA + 33554432);
  char* regB = ws + 58720256;                    // 50,331,648 B
  u16* qgkv_raw = (u16*)(regB);                  // phase B-C [4096][6144]
  u16* pre_out = (u16*)(regB);                   // phase D-E

  k_cvt<<<4096, 256, 0, stream>>>(tokens, tok_bf, 8388608);
  k_cvtT<<<dim3(96, 64), 256, 0, stream>>>(Wqg, WqgkvT, 2048, 3072);
  k_cvtT<<<dim3(96, 64), 256, 0, stream>>>(Wkv, WqgkvT + (size_t)3072 * 2048, 2048, 3072);
  k_cvtT<<<dim3(64, 64), 256, 0, stream>>>(Wo, WoT, 2048, 2048);

  k_gemm<0><<<dim3(48, 32), 256, 0, stream>>>(tok_bf, WqgkvT, qgkv_raw, 4096, 6144, 2048);

  k_norm<<<dim3(32, 32), 256, 0, stream>>>(qgkv_raw, qn, kn, vnT, gact);

  k_attn<<<dim3(16, 32), 256, 49152, stream>>>(qn, kn, vnT, gact, ls_iaw, ls_hws, pre_out);

  k_gemm<1><<<dim3(16, 32), 256, 0, stream>>>(pre_out, WoT, out, 4096, 2048, 2048);
}